// Round 10
// baseline (399.498 us; speedup 1.0000x reference)
//
#include <hip/hip_runtime.h>

#define DEV __device__ __forceinline__

typedef unsigned short u16;
typedef __bf16 bf16x8 __attribute__((ext_vector_type(8)));
typedef float f32x4 __attribute__((ext_vector_type(4)));
typedef unsigned short us8 __attribute__((ext_vector_type(8)));

// ---------------- problem constants ----------------
static constexpr int Bn = 4, Tn = 1024, Dn = 1024, Hn = 16, DFFn = 4096, En = 8;
static constexpr int Nn = Bn * Tn;        // 4096 tokens
static constexpr int MAXT64 = 72;         // 64-row grouped tiles (sum ceil(cnt/64) <= 72)
static constexpr int MAXT = 40;           // 128-row grouped tiles (reduce)
static constexpr int HROWS = 5120;        // 128-padded h rows

// meta layout (int indices)
static constexpr int MT64_E = 0, MT64_P0 = 72;       // 72 each
static constexpr int MT_E = 144, MT_P0 = 184;        // 40 each (reduce)
static constexpr int MCNT = 224, MCUR = 232, MSEG = 240, MPERM = 248;  // perm[5120]

// ---------------- ws layout (bytes) ----------------
static constexpr size_t WQKVT_O = 0;                                  // [3072][1024] bf16
static constexpr size_t WOT_O   = WQKVT_O + 3ull * 1024 * 1024 * 2;
static constexpr size_t W12T_O  = WOT_O + 1ull * 1024 * 1024 * 2;     // 8*[4096][1024] bf16 (W1T, later W2T)
static constexpr size_t X1F_O   = W12T_O + 8ull * 1024 * 4096 * 2;    // f32 [N][D]
static constexpr size_t XN_O    = X1F_O + (size_t)Nn * Dn * 4;        // xn bf16 / attn-out
static constexpr size_t Q_O     = XN_O + (size_t)Nn * Dn * 2;         // [B,H,T,DH] bf16
static constexpr size_t K_O     = Q_O + (size_t)Nn * Dn * 2;
static constexpr size_t VT_O    = K_O + (size_t)Nn * Dn * 2;          // [B,H,DH,T] bf16
static constexpr size_t X1B_O   = VT_O + (size_t)Nn * Dn * 2;         // bf16
static constexpr size_t P3_O    = XN_O;   // alias: bf16 [2][HROWS][D] = 20MB in dead XN..VT
static constexpr size_t H_O     = X1B_O + (size_t)Nn * Dn * 2;        // [HROWS][DFF] bf16
static constexpr size_t TOPP_O  = H_O + (size_t)HROWS * DFFn * 2;     // f32[N]
static constexpr size_t TIDX_O  = TOPP_O + (size_t)Nn * 4;            // int[N]
static constexpr size_t META_O  = TIDX_O + (size_t)Nn * 4;            // ints

// ---------------- helpers ----------------
DEV u16 f2bf(float f) {
  union { float f; unsigned u; } v; v.f = f;
  unsigned r = v.u + 0x7fffu + ((v.u >> 16) & 1u);
  return (u16)(r >> 16);
}
DEV float bf2f(u16 x) {
  union { unsigned u; float f; } v; v.u = ((unsigned)x) << 16;
  return v.f;
}

DEV void gload16(const void* g, void* l) {
  __builtin_amdgcn_global_load_lds(
      (__attribute__((address_space(1))) void*)(void*)g,
      (__attribute__((address_space(3))) void*)l, 16, 0, 0);
}

// swizzle for [R][64]bf16 tiles (128B rows): chunk c of row r at c ^ (r&7)
DEV void sdecode64(int o, int& row, int& c) {
  row = o >> 7;
  c = ((o >> 4) & 7) ^ (row & 7);
}

// attn tile swizzle [64 rows][64 bf16]
DEV int aswz(int r, int c) { return c ^ (r & 7) ^ (((r >> 3) & 3) << 1); }

// ---------------- merged transpose + cast for the four 1024x1024 weights ----------------
__global__ __launch_bounds__(256) void tcast4_kernel(
    const float* __restrict__ s0, const float* __restrict__ s1,
    const float* __restrict__ s2, const float* __restrict__ s3,
    u16* __restrict__ wqkvt, u16* __restrict__ wot) {
  __shared__ u16 tile[64][65];
  int z = blockIdx.z;
  const float* src = (z == 0) ? s0 : (z == 1) ? s1 : (z == 2) ? s2 : s3;
  u16* dst = (z < 3) ? wqkvt + (size_t)z * 1024 * 1024 : wot;
  int r0 = blockIdx.y * 64, c0 = blockIdx.x * 64;
  int tr = threadIdx.x >> 4;
  int tc = (threadIdx.x & 15) * 4;
#pragma unroll
  for (int i = 0; i < 4; i++) {
    int r = tr + i * 16;
    float4 v = *reinterpret_cast<const float4*>(&src[(long)(r0 + r) * 1024 + c0 + tc]);
    tile[r][tc + 0] = f2bf(v.x); tile[r][tc + 1] = f2bf(v.y);
    tile[r][tc + 2] = f2bf(v.z); tile[r][tc + 3] = f2bf(v.w);
  }
  __syncthreads();
#pragma unroll
  for (int i = 0; i < 4; i++) {
    int r = tr + i * 16;
    ushort4 o;
    o.x = tile[tc + 0][r]; o.y = tile[tc + 1][r];
    o.z = tile[tc + 2][r]; o.w = tile[tc + 3][r];
    *reinterpret_cast<ushort4*>(&dst[(long)(c0 + r) * 1024 + r0 + tc]) = o;
  }
}

// ---------------- transpose + cast (batched, for W1/W2) ----------------
__global__ __launch_bounds__(256) void tcast_kernel(
    const float* __restrict__ src, u16* __restrict__ dst,
    int R, int C, long srcBatch, long dstBatch) {
  __shared__ u16 tile[64][65];
  src += (long)blockIdx.z * srcBatch;
  dst += (long)blockIdx.z * dstBatch;
  int r0 = blockIdx.y * 64, c0 = blockIdx.x * 64;
  int tr = threadIdx.x >> 4;
  int tc = (threadIdx.x & 15) * 4;
#pragma unroll
  for (int i = 0; i < 4; i++) {
    int r = tr + i * 16;
    float4 v = *reinterpret_cast<const float4*>(&src[(long)(r0 + r) * C + c0 + tc]);
    tile[r][tc + 0] = f2bf(v.x); tile[r][tc + 1] = f2bf(v.y);
    tile[r][tc + 2] = f2bf(v.z); tile[r][tc + 3] = f2bf(v.w);
  }
  __syncthreads();
#pragma unroll
  for (int i = 0; i < 4; i++) {
    int r = tr + i * 16;
    ushort4 o;
    o.x = tile[tc + 0][r]; o.y = tile[tc + 1][r];
    o.z = tile[tc + 2][r]; o.w = tile[tc + 3][r];
    *reinterpret_cast<ushort4*>(&dst[(long)(c0 + r) * R + r0 + tc]) = o;
  }
}

// ---------------- LayerNorm (ddof=1, /(std+eps)) + bf16 cast ----------------
__global__ __launch_bounds__(256) void ln_kernel(
    const float* __restrict__ x, const float* __restrict__ a,
    const float* __restrict__ b, u16* __restrict__ xn) {
  __shared__ float red[8];
  int row = blockIdx.x, tid = threadIdx.x;
  int lane = tid & 63, w = tid >> 6;
  float4 v = *reinterpret_cast<const float4*>(&x[(size_t)row * 1024 + tid * 4]);
  float s = v.x + v.y + v.z + v.w;
  float sq = v.x * v.x + v.y * v.y + v.z * v.z + v.w * v.w;
#pragma unroll
  for (int sh = 1; sh <= 32; sh <<= 1) { s += __shfl_xor(s, sh); sq += __shfl_xor(sq, sh); }
  if (lane == 0) { red[w] = s; red[4 + w] = sq; }
  __syncthreads();
  s = red[0] + red[1] + red[2] + red[3];
  sq = red[4] + red[5] + red[6] + red[7];
  float mean = s * (1.0f / 1024.0f);
  float var = (sq - s * mean) * (1.0f / 1023.0f);
  float inv = 1.0f / (sqrtf(var) + 1e-6f);
  float4 av = *reinterpret_cast<const float4*>(&a[tid * 4]);
  float4 bv = *reinterpret_cast<const float4*>(&b[tid * 4]);
  ushort4 o;
  o.x = f2bf(av.x * (v.x - mean) * inv + bv.x);
  o.y = f2bf(av.y * (v.y - mean) * inv + bv.y);
  o.z = f2bf(av.z * (v.z - mean) * inv + bv.z);
  o.w = f2bf(av.w * (v.w - mean) * inv + bv.w);
  *reinterpret_cast<ushort4*>(&xn[(size_t)row * 1024 + tid * 4]) = o;
}

// ---------------- m97-structure GEMM engine, BM=64 high-occupancy variant ----------------
// 64x128 tile, BK=64, SINGLE 24KB LDS buffer, 2 barriers/K-step,
// global_load_lds w16, XOR swizzle, ~6 blocks/CU TLP, XCD+supertile remap.
// MODE 0: QKV fused -> q/k [B,H,T,DH] (Q pre-scaled 0.125), vt [B,H,DH,T]
// MODE 1: attn@WoT  -> x1f = x + acc + bo (f32), x1b (bf16)
// MODE 2: grouped FF1 (A row-gather, 64-row tiles) -> h = relu(acc + b1[e]) bf16
// MODE 3: grouped FF2 split-K (64-row tiles) -> pout bf16 partials
template <int MODE, int NG, int KSPLIT>
__global__ __launch_bounds__(256, 6) void gemm3_k(
    const u16* __restrict__ Ag, const u16* __restrict__ Bg,
    const float* __restrict__ f0, const float* __restrict__ f1,
    const float* __restrict__ f2, const float* __restrict__ xres,
    float* __restrict__ x1f, u16* __restrict__ ob0, u16* __restrict__ ob1,
    u16* __restrict__ ob2, u16* __restrict__ pout, const int* __restrict__ meta) {
  constexpr int K = (MODE == 3) ? 4096 : 1024;
  constexpr int KS = K / KSPLIT;
  constexpr int NSUB = KS >> 6;
  constexpr int MT = (MODE <= 1) ? 64 : MAXT64;
  constexpr int NT = (MODE == 0) ? 24 : (MODE == 2) ? 32 : 8;
  constexpr int WR = 32;    // per-wave rows
  constexpr int MI = 2;     // acc row-frags
  constexpr int CA = 2;     // A staging calls

  __shared__ u16 As[64 * 64];
  __shared__ u16 Bs[128 * 64];

  const int tid = threadIdx.x, lane = tid & 63, w = tid >> 6;
  const int wm = w >> 1, wn = w & 1;
  const int cL = lane >> 4, rl15 = lane & 15;

  constexpr int NWG = MT * NT * KSPLIT;
  constexpr int q8 = NWG >> 3;
  int b = blockIdx.x;
  int lg = (b & 7) * q8 + (b >> 3);
  constexpr int PERG = KSPLIT * MT * NG;
  int g = lg / PERG, rem = lg - g * PERG;
  int s = rem / (MT * NG); rem -= s * (MT * NG);
  int mt = rem / NG;
  int nt = g * NG + (rem - (rem / NG) * NG);

  int m0 = mt * 64, n0 = nt * 128;
  const int k0 = s * KS;
  const u16* Abase = Ag;
  const u16* Bbase = Bg;
  int e = 0, cnt = 0, seg = 0, pos0 = 0;
  if (MODE >= 2) {
    e = meta[MT64_E + mt];
    if (e < 0) return;
    cnt = meta[MCNT + e];
    seg = meta[MSEG + e];
    pos0 = meta[MT64_P0 + mt];
    Bbase = Bg + (size_t)e * 4096 * 1024;
    if (MODE == 3) Abase = Ag + (size_t)(seg + pos0) * 4096;
    m0 = 0;
  }

  const u16* gA[CA];
  const u16* gB[4];
#pragma unroll
  for (int j = 0; j < CA; j++) {
    int row, c;
    sdecode64(j * 4096 + tid * 16, row, c);
    if constexpr (MODE == 2) {
      int pos = pos0 + row; if (pos >= cnt) pos = cnt - 1;
      int tok = meta[MPERM + seg + pos];
      gA[j] = Ag + (size_t)tok * 1024 + k0 + c * 8;
    } else {
      gA[j] = Abase + (size_t)(m0 + row) * K + k0 + c * 8;
    }
  }
#pragma unroll
  for (int j = 0; j < 4; j++) {
    int row, c;
    sdecode64(j * 4096 + tid * 16, row, c);
    gB[j] = Bbase + (size_t)(n0 + row) * K + k0 + c * 8;
  }

  auto STAGE = [&](int t) {
#pragma unroll
    for (int j = 0; j < CA; j++)
      gload16(gA[j] + t * 64, &As[j * 2048 + tid * 8]);
#pragma unroll
    for (int j = 0; j < 4; j++)
      gload16(gB[j] + t * 64, &Bs[j * 2048 + tid * 8]);
  };

  f32x4 acc[MI][4] = {};
  const char* Ab = reinterpret_cast<const char*>(&As[0]);
  const char* Bb = reinterpret_cast<const char*>(&Bs[0]);

  STAGE(0);
  for (int t = 0; t < NSUB; t++) {
    asm volatile("s_waitcnt vmcnt(0)" ::: "memory");
    __builtin_amdgcn_s_barrier();
#pragma unroll
    for (int ph = 0; ph < 2; ph++) {
      bf16x8 af[MI], bfr[4];
#pragma unroll
      for (int mi = 0; mi < MI; mi++) {
        int row = wm * WR + mi * 16 + rl15;
        af[mi] = *reinterpret_cast<const bf16x8*>(
            Ab + row * 128 + ((ph * 64 + cL * 16) ^ ((row & 7) << 4)));
      }
#pragma unroll
      for (int ni = 0; ni < 4; ni++) {
        int row = wn * 64 + ni * 16 + rl15;
        bfr[ni] = *reinterpret_cast<const bf16x8*>(
            Bb + row * 128 + ((ph * 64 + cL * 16) ^ ((row & 7) << 4)));
      }
#pragma unroll
      for (int mi = 0; mi < MI; mi++)
#pragma unroll
        for (int ni = 0; ni < 4; ni++)
          acc[mi][ni] = __builtin_amdgcn_mfma_f32_16x16x32_bf16(
              af[mi], bfr[ni], acc[mi][ni], 0, 0, 0);
    }
    __builtin_amdgcn_s_barrier();
    if (t + 1 < NSUB) STAGE(t + 1);
  }

  const int cl = rl15, rl = cL;
  if (MODE == 0) {
    int third = n0 >> 10;
    const float* bias = (third == 0) ? f0 : (third == 1) ? f1 : f2;
    const float qs = (third == 0) ? 0.125f : 1.0f;  // fold attn scale into Q
#pragma unroll
    for (int ni = 0; ni < 4; ni++) {
      int col = n0 + wn * 64 + ni * 16 + cl;
      int jj = col & 1023;
      float bb_ = bias[jj];
      int hh = jj >> 6, dd = jj & 63;
#pragma unroll
      for (int mi = 0; mi < MI; mi++) {
        int t0 = m0 + wm * WR + mi * 16 + rl * 4;
        int b_ = t0 >> 10, tt = t0 & 1023;
        size_t bh = (size_t)(b_ * Hn + hh);
        if (third == 2) {
          ushort4 o4;
          o4.x = f2bf(acc[mi][ni][0] + bb_); o4.y = f2bf(acc[mi][ni][1] + bb_);
          o4.z = f2bf(acc[mi][ni][2] + bb_); o4.w = f2bf(acc[mi][ni][3] + bb_);
          *reinterpret_cast<ushort4*>(&ob2[(bh * 64 + dd) * 1024 + tt]) = o4;
        } else {
          u16* dst = (third == 0) ? ob0 : ob1;
#pragma unroll
          for (int r = 0; r < 4; r++)
            dst[(bh * 1024 + tt + r) * 64 + dd] = f2bf((acc[mi][ni][r] + bb_) * qs);
        }
      }
    }
  } else if (MODE == 1) {
#pragma unroll
    for (int ni = 0; ni < 4; ni++) {
      int col = n0 + wn * 64 + ni * 16 + cl;
      float bo_ = f0[col];
#pragma unroll
      for (int mi = 0; mi < MI; mi++) {
        int row = m0 + wm * WR + mi * 16 + rl * 4;
#pragma unroll
        for (int r = 0; r < 4; r++) {
          size_t idx = (size_t)(row + r) * 1024 + col;
          float v = acc[mi][ni][r] + bo_ + xres[idx];
          x1f[idx] = v;
          ob0[idx] = f2bf(v);
        }
      }
    }
  } else if (MODE == 2) {
#pragma unroll
    for (int ni = 0; ni < 4; ni++) {
      int col = n0 + wn * 64 + ni * 16 + cl;
      float b1_ = f0[(size_t)e * 4096 + col];
#pragma unroll
      for (int mi = 0; mi < MI; mi++) {
        int pos = pos0 + wm * WR + mi * 16 + rl * 4;
#pragma unroll
        for (int r = 0; r < 4; r++) {
          float v = acc[mi][ni][r] + b1_;
          v = v > 0.0f ? v : 0.0f;
          ob0[(size_t)(seg + pos + r) * 4096 + col] = f2bf(v);
        }
      }
    }
  } else {  // MODE 3: bf16 partials (padded rows included; reduce masks)
#pragma unroll
    for (int ni = 0; ni < 4; ni++) {
      int col = n0 + wn * 64 + ni * 16 + cl;
#pragma unroll
      for (int mi = 0; mi < MI; mi++) {
        int pos = pos0 + wm * WR + mi * 16 + rl * 4;
#pragma unroll
        for (int r = 0; r < 4; r++)
          pout[((size_t)s * HROWS + seg + pos + r) * 1024 + col] = f2bf(acc[mi][ni][r]);
      }
    }
  }
}

// ---------------- FF2 split-K reduce: out = x1f + topp*(p0+p1+b2[e]) ----------------
__global__ __launch_bounds__(256) void reduce3_kernel(
    const u16* __restrict__ P3, const float* __restrict__ x1f,
    const float* __restrict__ topp, const float* __restrict__ b2,
    const int* __restrict__ meta, float* __restrict__ out) {
  int bidx = blockIdx.x;
  int tile = bidx >> 7, rowin = bidx & 127;
  int e = meta[MT_E + tile];
  if (e < 0) return;
  int cnt = meta[MCNT + e], seg = meta[MSEG + e];
  int pos = meta[MT_P0 + tile] + rowin;
  if (pos >= cnt) return;
  int tok = meta[MPERM + seg + pos];
  size_t prow = (size_t)(seg + pos) * 1024;
  float p = topp[tok];
  int c = threadIdx.x * 4;
  ushort4 u0 = *reinterpret_cast<const ushort4*>(&P3[prow + c]);
  ushort4 u1 = *reinterpret_cast<const ushort4*>(&P3[(size_t)HROWS * 1024 + prow + c]);
  float4 xr = *reinterpret_cast<const float4*>(&x1f[(size_t)tok * 1024 + c]);
  float4 bb = *reinterpret_cast<const float4*>(&b2[e * 1024 + c]);
  float4 o;
  o.x = xr.x + p * (bf2f(u0.x) + bf2f(u1.x) + bb.x);
  o.y = xr.y + p * (bf2f(u0.y) + bf2f(u1.y) + bb.y);
  o.z = xr.z + p * (bf2f(u0.z) + bf2f(u1.z) + bb.z);
  o.w = xr.w + p * (bf2f(u0.w) + bf2f(u1.w) + bb.w);
  *reinterpret_cast<float4*>(&out[(size_t)tok * 1024 + c]) = o;
}

// ---------------- flash attention, swapped-operand + staged epilogue ----------------
__global__ __launch_bounds__(256, 4) void attn_kernel(
    const u16* __restrict__ q, const u16* __restrict__ k,
    const u16* __restrict__ vt, u16* __restrict__ attn) {
  __shared__ u16 Ks[2][64 * 64];
  __shared__ u16 Vs[2][64 * 64];
  const int tid = threadIdx.x, lane = tid & 63, w = tid >> 6;
  const int g = lane >> 4, l15 = lane & 15;

  int bb = blockIdx.x;
  int lg = (bb & 7) * 128 + (bb >> 3);
  const int bh = lg >> 4;
  const int qt = lg & 15;
  const size_t qkbase = (size_t)bh * Tn * 64;
  const size_t vtbase = (size_t)bh * 64 * Tn;
  const int qrow0 = qt * 64 + w * 16;

  bf16x8 qf[2];
  {
    const u16* qp = q + qkbase + (size_t)(qrow0 + l15) * 64 + g * 8;
    qf[0] = *reinterpret_cast<const bf16x8*>(qp);
    qf[1] = *reinterpret_cast<const bf16x8*>(qp + 32);
  }

  const u16* gk[2];
  const u16* gv[2];
#pragma unroll
  for (int j = 0; j < 2; j++) {
    int sidx = j * 256 + tid;
    int r = sidx >> 3, p = sidx & 7;
    int c = aswz(r, p);
    gk[j] = k + qkbase + (size_t)r * 64 + c * 8;
    gv[j] = vt + vtbase + (size_t)r * Tn + c * 8;
  }

  auto STAGE = [&](int t) {
    int buf = t & 1;
#pragma unroll
    for (int j = 0; j < 2; j++) {
      int sidx = j * 256 + tid;
      gload16(gk[j] + (size_t)t * 4096, &Ks[buf][sidx * 8]);
      gload16(gv[j] + (size_t)t * 64, &Vs[buf][sidx * 8]);
    }
  };

  f32x4 o[4] = {};
  float mrun = -1e30f, lsum = 0.0f;

  STAGE(0);
  for (int t = 0; t < 16; t++) {
    asm volatile("s_waitcnt vmcnt(0)" ::: "memory");
    __builtin_amdgcn_s_barrier();
    if (t + 1 < 16) STAGE(t + 1);

    const char* Kb = reinterpret_cast<const char*>(&Ks[t & 1][0]);
    const char* Vb = reinterpret_cast<const char*>(&Vs[t & 1][0]);

    f32x4 sk[2][2];
#pragma unroll
    for (int kb = 0; kb < 2; kb++)
#pragma unroll
      for (int m = 0; m < 2; m++) {
        f32x4 sa = {};
#pragma unroll
        for (int ph = 0; ph < 2; ph++) {
          int ksel = kb * 32 + (l15 >> 2) * 8 + m * 4 + (lane & 3);
          int pch = aswz(ksel, g + ph * 4);
          bf16x8 kf = *reinterpret_cast<const bf16x8*>(Kb + ksel * 128 + pch * 16);
          sa = __builtin_amdgcn_mfma_f32_16x16x32_bf16(kf, qf[ph], sa, 0, 0, 0);
        }
        sk[kb][m] = sa;
      }

    float mx = -1e30f;
#pragma unroll
    for (int kb = 0; kb < 2; kb++)
#pragma unroll
      for (int m = 0; m < 2; m++)
#pragma unroll
        for (int r = 0; r < 4; r++) mx = fmaxf(mx, sk[kb][m][r]);
    mx = fmaxf(mx, __shfl_xor(mx, 16));
    mx = fmaxf(mx, __shfl_xor(mx, 32));
    float mn = fmaxf(mrun, mx);
    float rsc = __expf(mrun - mn);
    mrun = mn;

    float pv[2][8];
    float ps = 0.0f;
#pragma unroll
    for (int kb = 0; kb < 2; kb++)
#pragma unroll
      for (int m = 0; m < 2; m++)
#pragma unroll
        for (int r = 0; r < 4; r++) {
          float pe = __expf(sk[kb][m][r] - mn);
          pv[kb][m * 4 + r] = pe;
          ps += pe;
        }
    ps += __shfl_xor(ps, 16);
    ps += __shfl_xor(ps, 32);
    lsum = lsum * rsc + ps;
#pragma unroll
    for (int nf = 0; nf < 4; nf++)
#pragma unroll
      for (int r = 0; r < 4; r++) o[nf][r] *= rsc;

    bf16x8 pf[2];
#pragma unroll
    for (int kb = 0; kb < 2; kb++)
#pragma unroll
      for (int j = 0; j < 8; j++) pf[kb][j] = (__bf16)pv[kb][j];

#pragma unroll
    for (int nf = 0; nf < 4; nf++) {
      int d = nf * 16 + l15;
#pragma unroll
      for (int kb = 0; kb < 2; kb++) {
        int pch = aswz(d, g + kb * 4);
        bf16x8 vf = *reinterpret_cast<const bf16x8*>(Vb + d * 128 + pch * 16);
        o[nf] = __builtin_amdgcn_mfma_f32_16x16x32_bf16(vf, pf[kb], o[nf], 0, 0, 0);
      }
    }
  }

  // staged epilogue: [64 q][64 d] tile in Ks, then ushort8 coalesced stores
  __syncthreads();
  u16* T = &Ks[0][0];
  float inv = 1.0f / lsum;
#pragma unroll
  for (int nf = 0; nf < 4; nf++)
#pragma unroll
    for (int r = 0; r < 4; r++) {
      int row = w * 16 + l15;
      int d = nf * 16 + g * 4 + r;
      int off = (row << 6) + ((((d >> 3) ^ (row & 7)) << 3) | (d & 7));
      T[off] = f2bf(o[nf][r] * inv);
    }
  __syncthreads();
  int b_ = bh >> 4, h_ = bh & 15;
#pragma unroll
  for (int p = 0; p < 2; p++) {
    int idx = p * 256 + tid;
    int row = idx >> 3, ch = idx & 7;
    int pch = ch ^ (row & 7);
    us8 v = *reinterpret_cast<const us8*>(T + (row << 6) + (pch << 3));
    *reinterpret_cast<us8*>(
        &attn[((size_t)(b_ * Tn + qt * 64 + row)) * 1024 + h_ * 64 + ch * 8]) = v;
  }
}

// ---------------- MoE gate: f32 logits, softmax, top-1 ----------------
__global__ __launch_bounds__(256) void gate_kernel(
    const float* __restrict__ x1f, const float* __restrict__ gW,
    const float* __restrict__ gb, float* __restrict__ topp,
    int* __restrict__ tidx, int* __restrict__ meta) {
  int lane = threadIdx.x & 63;
  int n = blockIdx.x * 4 + (threadIdx.x >> 6);
  float acc[8] = {};
  const float* xr = x1f + (size_t)n * 1024;
  for (int kk = 0; kk < 16; kk++) {
    int kcol = kk * 64 + lane;
    float xv = xr[kcol];
    float4 g0 = *reinterpret_cast<const float4*>(&gW[kcol * 8]);
    float4 g1 = *reinterpret_cast<const float4*>(&gW[kcol * 8 + 4]);
    acc[0] = fmaf(xv, g0.x, acc[0]); acc[1] = fmaf(xv, g0.y, acc[1]);
    acc[2] = fmaf(xv, g0.z, acc[2]); acc[3] = fmaf(xv, g0.w, acc[3]);
    acc[4] = fmaf(xv, g1.x, acc[4]); acc[5] = fmaf(xv, g1.y, acc[5]);
    acc[6] = fmaf(xv, g1.z, acc[6]); acc[7] = fmaf(xv, g1.w, acc[7]);
  }
#pragma unroll
  for (int e2 = 0; e2 < 8; e2++)
#pragma unroll
    for (int sh = 1; sh <= 32; sh <<= 1) acc[e2] += __shfl_xor(acc[e2], sh);
  if (lane == 0) {
    float best = -1e30f; int bi = 0;
#pragma unroll
    for (int e2 = 0; e2 < 8; e2++) {
      float lgt = acc[e2] + gb[e2];
      if (lgt > best) { best = lgt; bi = e2; }
    }
    float den = 0.0f;
#pragma unroll
    for (int e2 = 0; e2 < 8; e2++) den += __expf(acc[e2] + gb[e2] - best);
    topp[n] = 1.0f / den;
    tidx[n] = bi;
    atomicAdd(&meta[MCNT + bi], 1);
  }
}

// ---------------- scan: 128-padded segments, 64- and 128-row tile tables, aux ----------------
__global__ void scan_kernel(int* meta, float* aux_out) {
  if (threadIdx.x == 0) {
    int sb = 0, t64 = 0, t1 = 0;
    float aux = 0.0f;
    for (int e2 = 0; e2 < 8; e2++) {
      meta[MSEG + e2] = sb;
      int c = meta[MCNT + e2];
      int n64 = (c + 63) >> 6;
      for (int i = 0; i < n64; i++) { meta[MT64_E + t64] = e2; meta[MT64_P0 + t64] = i * 64; t64++; }
      int n1 = (c + 127) >> 7;
      for (int i = 0; i < n1; i++) { meta[MT_E + t1] = e2; meta[MT_P0 + t1] = i * 128; t1++; }
      sb += n1 << 7;
      float fr = (float)c * (1.0f / 4096.0f);
      aux += fr * fr;
    }
    for (; t64 < MAXT64; t64++) { meta[MT64_E + t64] = -1; meta[MT64_P0 + t64] = 0; }
    for (; t1 < MAXT; t1++) { meta[MT_E + t1] = -1; meta[MT_P0 + t1] = 0; }
    aux_out[0] = aux * 8.0f;
  }
}

__global__ __launch_bounds__(256) void scatter_kernel(const int* __restrict__ tidx, int* meta) {
  int n = blockIdx.x * 256 + threadIdx.x;
  int e2 = tidx[n];
  int pos = atomicAdd(&meta[MCUR + e2], 1);
  meta[MPERM + meta[MSEG + e2] + pos] = n;
}

// ---------------- launch ----------------
extern "C" void kernel_launch(void* const* d_in, const int* in_sizes, int n_in,
                              void* d_out, int out_size, void* d_ws, size_t ws_size,
                              hipStream_t stream) {
  const float* x   = (const float*)d_in[0];
  const float* Wq  = (const float*)d_in[2];
  const float* bq  = (const float*)d_in[3];
  const float* Wk  = (const float*)d_in[4];
  const float* bk  = (const float*)d_in[5];
  const float* Wv  = (const float*)d_in[6];
  const float* bv  = (const float*)d_in[7];
  const float* Wo  = (const float*)d_in[8];
  const float* bo  = (const float*)d_in[9];
  const float* ln1a = (const float*)d_in[10];
  const float* ln1b = (const float*)d_in[11];
  const float* gW  = (const float*)d_in[14];
  const float* gb  = (const float*)d_in[15];
  const float* W1  = (const float*)d_in[16];
  const float* b1  = (const float*)d_in[17];
  const float* W2  = (const float*)d_in[18];
  const float* b2  = (const float*)d_in[19];
  float* out = (float*)d_out;
  char* ws = (char*)d_ws;

  u16* wqkvt = (u16*)(ws + WQKVT_O);
  u16* wot   = (u16*)(ws + WOT_O);
  u16* w12t  = (u16*)(ws + W12T_O);
  u16* xn    = (u16*)(ws + XN_O);
  u16* qb    = (u16*)(ws + Q_O);
  u16* kb    = (u16*)(ws + K_O);
  u16* vtb   = (u16*)(ws + VT_O);
  float* x1f = (float*)(ws + X1F_O);
  u16* x1b   = (u16*)(ws + X1B_O);
  u16* p3    = (u16*)(ws + P3_O);
  u16* hb    = (u16*)(ws + H_O);
  float* topp = (float*)(ws + TOPP_O);
  int* tidx  = (int*)(ws + TIDX_O);
  int* meta  = (int*)(ws + META_O);

  hipMemsetAsync(meta + MCNT, 0, 16 * sizeof(int), stream);

  tcast4_kernel<<<dim3(16, 16, 4), 256, 0, stream>>>(Wq, Wk, Wv, Wo, wqkvt, wot);
  tcast_kernel<<<dim3(64, 16, 8), 256, 0, stream>>>(W1, w12t, 1024, 4096,
                                                    (long)1024 * 4096, (long)4096 * 1024);

  ln_kernel<<<4096, 256, 0, stream>>>(x, ln1a, ln1b, xn);
  gemm3_k<0, 4, 1><<<1536, 256, 0, stream>>>(xn, wqkvt, bq, bk, bv, nullptr, nullptr,
                                             qb, kb, vtb, nullptr, meta);
  attn_kernel<<<1024, 256, 0, stream>>>(qb, kb, vtb, xn);  // xn reused as attn-out
  gemm3_k<1, 4, 1><<<512, 256, 0, stream>>>(xn, wot, bo, nullptr, nullptr, x, x1f,
                                            x1b, nullptr, nullptr, nullptr, meta);
  gate_kernel<<<1024, 256, 0, stream>>>(x1f, gW, gb, topp, tidx, meta);
  scan_kernel<<<1, 64, 0, stream>>>(meta, out + (size_t)Nn * Dn);
  scatter_kernel<<<16, 256, 0, stream>>>(tidx, meta);
  gemm3_k<2, 4, 1><<<2304, 256, 0, stream>>>(x1b, w12t, b1, nullptr, nullptr, nullptr,
                                             nullptr, hb, nullptr, nullptr, nullptr, meta);
  tcast_kernel<<<dim3(16, 64, 8), 256, 0, stream>>>(W2, w12t, 4096, 1024,
                                                    (long)4096 * 1024, (long)1024 * 4096);
  gemm3_k<3, 2, 2><<<1152, 256, 0, stream>>>(hb, w12t, nullptr, nullptr, nullptr, nullptr,
                                             nullptr, nullptr, nullptr, nullptr, p3, meta);
  reduce3_kernel<<<MAXT * 128, 256, 0, stream>>>(p3, x1f, topp, b2, meta, out);
}

// Round 11
// 379.000 us; speedup vs baseline: 1.0541x; 1.0541x over previous
//
#include <hip/hip_runtime.h>

#define DEV __device__ __forceinline__

typedef unsigned short u16;
typedef __bf16 bf16x8 __attribute__((ext_vector_type(8)));
typedef float f32x4 __attribute__((ext_vector_type(4)));
typedef unsigned short us8 __attribute__((ext_vector_type(8)));

// ---------------- problem constants ----------------
static constexpr int Bn = 4, Tn = 1024, Dn = 1024, Hn = 16, DFFn = 4096, En = 8;
static constexpr int Nn = Bn * Tn;        // 4096 tokens
static constexpr int MAXT = 40;           // max grouped M-tiles (128-row)
static constexpr int HROWS = 5120;        // 128-padded h rows

// meta layout (int indices)  [R4/R9-proven]
static constexpr int MT_E = 0, MT_P0 = 40, MCNT = 80, MCUR = 88, MSEG = 96, MPERM = 112;

// ---------------- ws layout (bytes) ----------------
static constexpr size_t WQKVT_O = 0;                                  // [3072][1024] bf16
static constexpr size_t WOT_O   = WQKVT_O + 3ull * 1024 * 1024 * 2;
static constexpr size_t W12T_O  = WOT_O + 1ull * 1024 * 1024 * 2;     // 8*[4096][1024] bf16 (W1T, later W2T)
static constexpr size_t X1F_O   = W12T_O + 8ull * 1024 * 4096 * 2;    // f32 [N][D]
static constexpr size_t XN_O    = X1F_O + (size_t)Nn * Dn * 4;        // xn bf16 / attn-out
static constexpr size_t Q_O     = XN_O + (size_t)Nn * Dn * 2;         // [B,H,T,DH] bf16
static constexpr size_t K_O     = Q_O + (size_t)Nn * Dn * 2;
static constexpr size_t VT_O    = K_O + (size_t)Nn * Dn * 2;          // [B,H,DH,T] bf16
static constexpr size_t X1B_O   = VT_O + (size_t)Nn * Dn * 2;         // bf16
static constexpr size_t P3_O    = XN_O;   // alias: bf16 [2][HROWS][D] = 20MB in dead XN..VT
static constexpr size_t H_O     = X1B_O + (size_t)Nn * Dn * 2;        // [HROWS][DFF] bf16
static constexpr size_t TOPP_O  = H_O + (size_t)HROWS * DFFn * 2;     // f32[N]
static constexpr size_t TIDX_O  = TOPP_O + (size_t)Nn * 4;            // int[N]
static constexpr size_t META_O  = TIDX_O + (size_t)Nn * 4;            // ints

// ---------------- helpers ----------------
DEV u16 f2bf(float f) {
  union { float f; unsigned u; } v; v.f = f;
  unsigned r = v.u + 0x7fffu + ((v.u >> 16) & 1u);
  return (u16)(r >> 16);
}
DEV float bf2f(u16 x) {
  union { unsigned u; float f; } v; v.u = ((unsigned)x) << 16;
  return v.f;
}

DEV void gload16(const void* g, void* l) {
  __builtin_amdgcn_global_load_lds(
      (__attribute__((address_space(1))) void*)(void*)g,
      (__attribute__((address_space(3))) void*)l, 16, 0, 0);
}

// swizzle for [R][64]bf16 tiles (128B rows): chunk c of row r at c ^ (r&7)
DEV void sdecode64(int o, int& row, int& c) {
  row = o >> 7;
  c = ((o >> 4) & 7) ^ (row & 7);
}

// attn tile swizzle [64 rows][64 bf16]
DEV int aswz(int r, int c) { return c ^ (r & 7) ^ (((r >> 3) & 3) << 1); }

// ---------------- merged transpose + cast for the four 1024x1024 weights ----------------
__global__ __launch_bounds__(256) void tcast4_kernel(
    const float* __restrict__ s0, const float* __restrict__ s1,
    const float* __restrict__ s2, const float* __restrict__ s3,
    u16* __restrict__ wqkvt, u16* __restrict__ wot) {
  __shared__ u16 tile[64][65];
  int z = blockIdx.z;
  const float* src = (z == 0) ? s0 : (z == 1) ? s1 : (z == 2) ? s2 : s3;
  u16* dst = (z < 3) ? wqkvt + (size_t)z * 1024 * 1024 : wot;
  int r0 = blockIdx.y * 64, c0 = blockIdx.x * 64;
  int tr = threadIdx.x >> 4;
  int tc = (threadIdx.x & 15) * 4;
#pragma unroll
  for (int i = 0; i < 4; i++) {
    int r = tr + i * 16;
    float4 v = *reinterpret_cast<const float4*>(&src[(long)(r0 + r) * 1024 + c0 + tc]);
    tile[r][tc + 0] = f2bf(v.x); tile[r][tc + 1] = f2bf(v.y);
    tile[r][tc + 2] = f2bf(v.z); tile[r][tc + 3] = f2bf(v.w);
  }
  __syncthreads();
#pragma unroll
  for (int i = 0; i < 4; i++) {
    int r = tr + i * 16;
    ushort4 o;
    o.x = tile[tc + 0][r]; o.y = tile[tc + 1][r];
    o.z = tile[tc + 2][r]; o.w = tile[tc + 3][r];
    *reinterpret_cast<ushort4*>(&dst[(long)(c0 + r) * 1024 + r0 + tc]) = o;
  }
}

// ---------------- transpose + cast (batched, for W1/W2) ----------------
__global__ __launch_bounds__(256) void tcast_kernel(
    const float* __restrict__ src, u16* __restrict__ dst,
    int R, int C, long srcBatch, long dstBatch) {
  __shared__ u16 tile[64][65];
  src += (long)blockIdx.z * srcBatch;
  dst += (long)blockIdx.z * dstBatch;
  int r0 = blockIdx.y * 64, c0 = blockIdx.x * 64;
  int tr = threadIdx.x >> 4;
  int tc = (threadIdx.x & 15) * 4;
#pragma unroll
  for (int i = 0; i < 4; i++) {
    int r = tr + i * 16;
    float4 v = *reinterpret_cast<const float4*>(&src[(long)(r0 + r) * C + c0 + tc]);
    tile[r][tc + 0] = f2bf(v.x); tile[r][tc + 1] = f2bf(v.y);
    tile[r][tc + 2] = f2bf(v.z); tile[r][tc + 3] = f2bf(v.w);
  }
  __syncthreads();
#pragma unroll
  for (int i = 0; i < 4; i++) {
    int r = tr + i * 16;
    ushort4 o;
    o.x = tile[tc + 0][r]; o.y = tile[tc + 1][r];
    o.z = tile[tc + 2][r]; o.w = tile[tc + 3][r];
    *reinterpret_cast<ushort4*>(&dst[(long)(c0 + r) * R + r0 + tc]) = o;
  }
}

// ---------------- LayerNorm (ddof=1, /(std+eps)) + bf16 cast ----------------
__global__ __launch_bounds__(256) void ln_kernel(
    const float* __restrict__ x, const float* __restrict__ a,
    const float* __restrict__ b, u16* __restrict__ xn) {
  __shared__ float red[8];
  int row = blockIdx.x, tid = threadIdx.x;
  int lane = tid & 63, w = tid >> 6;
  float4 v = *reinterpret_cast<const float4*>(&x[(size_t)row * 1024 + tid * 4]);
  float s = v.x + v.y + v.z + v.w;
  float sq = v.x * v.x + v.y * v.y + v.z * v.z + v.w * v.w;
#pragma unroll
  for (int sh = 1; sh <= 32; sh <<= 1) { s += __shfl_xor(s, sh); sq += __shfl_xor(sq, sh); }
  if (lane == 0) { red[w] = s; red[4 + w] = sq; }
  __syncthreads();
  s = red[0] + red[1] + red[2] + red[3];
  sq = red[4] + red[5] + red[6] + red[7];
  float mean = s * (1.0f / 1024.0f);
  float var = (sq - s * mean) * (1.0f / 1023.0f);
  float inv = 1.0f / (sqrtf(var) + 1e-6f);
  float4 av = *reinterpret_cast<const float4*>(&a[tid * 4]);
  float4 bv = *reinterpret_cast<const float4*>(&b[tid * 4]);
  ushort4 o;
  o.x = f2bf(av.x * (v.x - mean) * inv + bv.x);
  o.y = f2bf(av.y * (v.y - mean) * inv + bv.y);
  o.z = f2bf(av.z * (v.z - mean) * inv + bv.z);
  o.w = f2bf(av.w * (v.w - mean) * inv + bv.w);
  *reinterpret_cast<ushort4*>(&xn[(size_t)row * 1024 + tid * 4]) = o;
}

// ---------------- m97-structure GEMM engine (R9-proven, best config) ----------------
// BM x 128 tile, BK=64, SINGLE 32KB LDS buffer, 2 barriers/K-step,
// global_load_lds w16, XOR swizzle, 3 blocks/CU TLP, XCD+supertile remap.
// MODE 0: QKV fused -> q/k [B,H,T,DH] (Q pre-scaled 0.125), vt [B,H,DH,T]
// MODE 1: attn@WoT  -> x1f = x + acc + bo (f32), x1b (bf16)
// MODE 2: grouped FF1 (A row-gather) -> h = relu(acc + b1[e]) bf16
// MODE 3: grouped FF2 split-K -> pout bf16 partials
template <int MODE, int BM, int NG, int KSPLIT>
__global__ __launch_bounds__(256, 3) void gemm3_k(
    const u16* __restrict__ Ag, const u16* __restrict__ Bg,
    const float* __restrict__ f0, const float* __restrict__ f1,
    const float* __restrict__ f2, const float* __restrict__ xres,
    float* __restrict__ x1f, u16* __restrict__ ob0, u16* __restrict__ ob1,
    u16* __restrict__ ob2, u16* __restrict__ pout, const int* __restrict__ meta) {
  constexpr int K = (MODE == 3) ? 4096 : 1024;
  constexpr int KS = K / KSPLIT;
  constexpr int NSUB = KS >> 6;
  constexpr int MT = (MODE <= 1) ? (4096 / BM) : MAXT;
  constexpr int NT = (MODE == 0) ? 24 : (MODE == 2) ? 32 : 8;
  constexpr int WR = BM / 2;
  constexpr int MI = WR / 16;
  constexpr int CA = BM / 32;

  __shared__ u16 As[BM * 64];
  __shared__ u16 Bs[128 * 64];

  const int tid = threadIdx.x, lane = tid & 63, w = tid >> 6;
  const int wm = w >> 1, wn = w & 1;
  const int cL = lane >> 4, rl15 = lane & 15;

  constexpr int NWG = MT * NT * KSPLIT;
  constexpr int q8 = NWG >> 3;
  int b = blockIdx.x;
  int lg = (b & 7) * q8 + (b >> 3);
  constexpr int PERG = KSPLIT * MT * NG;
  int g = lg / PERG, rem = lg - g * PERG;
  int s = rem / (MT * NG); rem -= s * (MT * NG);
  int mt = rem / NG;
  int nt = g * NG + (rem - (rem / NG) * NG);

  int m0 = mt * BM, n0 = nt * 128;
  const int k0 = s * KS;
  const u16* Abase = Ag;
  const u16* Bbase = Bg;
  int e = 0, cnt = 0, seg = 0, pos0 = 0;
  if (MODE >= 2) {
    e = meta[MT_E + mt];
    if (e < 0) return;
    cnt = meta[MCNT + e];
    seg = meta[MSEG + e];
    pos0 = meta[MT_P0 + mt];
    Bbase = Bg + (size_t)e * 4096 * 1024;
    if (MODE == 3) Abase = Ag + (size_t)(seg + pos0) * 4096;
    m0 = 0;
  }

  const u16* gA[CA];
  const u16* gB[4];
#pragma unroll
  for (int j = 0; j < CA; j++) {
    int row, c;
    sdecode64(j * 4096 + tid * 16, row, c);
    if constexpr (MODE == 2) {
      int pos = pos0 + row; if (pos >= cnt) pos = cnt - 1;
      int tok = meta[MPERM + seg + pos];
      gA[j] = Ag + (size_t)tok * 1024 + k0 + c * 8;
    } else {
      gA[j] = Abase + (size_t)(m0 + row) * K + k0 + c * 8;
    }
  }
#pragma unroll
  for (int j = 0; j < 4; j++) {
    int row, c;
    sdecode64(j * 4096 + tid * 16, row, c);
    gB[j] = Bbase + (size_t)(n0 + row) * K + k0 + c * 8;
  }

  auto STAGE = [&](int t) {
#pragma unroll
    for (int j = 0; j < CA; j++)
      gload16(gA[j] + t * 64, &As[j * 2048 + tid * 8]);
#pragma unroll
    for (int j = 0; j < 4; j++)
      gload16(gB[j] + t * 64, &Bs[j * 2048 + tid * 8]);
  };

  f32x4 acc[MI][4] = {};
  const char* Ab = reinterpret_cast<const char*>(&As[0]);
  const char* Bb = reinterpret_cast<const char*>(&Bs[0]);

  STAGE(0);
  for (int t = 0; t < NSUB; t++) {
    asm volatile("s_waitcnt vmcnt(0)" ::: "memory");
    __builtin_amdgcn_s_barrier();
#pragma unroll
    for (int ph = 0; ph < 2; ph++) {
      bf16x8 af[MI], bfr[4];
#pragma unroll
      for (int mi = 0; mi < MI; mi++) {
        int row = wm * WR + mi * 16 + rl15;
        af[mi] = *reinterpret_cast<const bf16x8*>(
            Ab + row * 128 + ((ph * 64 + cL * 16) ^ ((row & 7) << 4)));
      }
#pragma unroll
      for (int ni = 0; ni < 4; ni++) {
        int row = wn * 64 + ni * 16 + rl15;
        bfr[ni] = *reinterpret_cast<const bf16x8*>(
            Bb + row * 128 + ((ph * 64 + cL * 16) ^ ((row & 7) << 4)));
      }
#pragma unroll
      for (int mi = 0; mi < MI; mi++)
#pragma unroll
        for (int ni = 0; ni < 4; ni++)
          acc[mi][ni] = __builtin_amdgcn_mfma_f32_16x16x32_bf16(
              af[mi], bfr[ni], acc[mi][ni], 0, 0, 0);
    }
    __builtin_amdgcn_s_barrier();
    if (t + 1 < NSUB) STAGE(t + 1);
  }

  const int cl = rl15, rl = cL;
  if (MODE == 0) {
    int third = n0 >> 10;
    const float* bias = (third == 0) ? f0 : (third == 1) ? f1 : f2;
    const float qs = (third == 0) ? 0.125f : 1.0f;  // fold attn scale into Q
#pragma unroll
    for (int ni = 0; ni < 4; ni++) {
      int col = n0 + wn * 64 + ni * 16 + cl;
      int jj = col & 1023;
      float bb_ = bias[jj];
      int hh = jj >> 6, dd = jj & 63;
#pragma unroll
      for (int mi = 0; mi < MI; mi++) {
        int t0 = m0 + wm * WR + mi * 16 + rl * 4;
        int b_ = t0 >> 10, tt = t0 & 1023;
        size_t bh = (size_t)(b_ * Hn + hh);
        if (third == 2) {
          ushort4 o4;
          o4.x = f2bf(acc[mi][ni][0] + bb_); o4.y = f2bf(acc[mi][ni][1] + bb_);
          o4.z = f2bf(acc[mi][ni][2] + bb_); o4.w = f2bf(acc[mi][ni][3] + bb_);
          *reinterpret_cast<ushort4*>(&ob2[(bh * 64 + dd) * 1024 + tt]) = o4;
        } else {
          u16* dst = (third == 0) ? ob0 : ob1;
#pragma unroll
          for (int r = 0; r < 4; r++)
            dst[(bh * 1024 + tt + r) * 64 + dd] = f2bf((acc[mi][ni][r] + bb_) * qs);
        }
      }
    }
  } else if (MODE == 1) {
#pragma unroll
    for (int ni = 0; ni < 4; ni++) {
      int col = n0 + wn * 64 + ni * 16 + cl;
      float bo_ = f0[col];
#pragma unroll
      for (int mi = 0; mi < MI; mi++) {
        int row = m0 + wm * WR + mi * 16 + rl * 4;
#pragma unroll
        for (int r = 0; r < 4; r++) {
          size_t idx = (size_t)(row + r) * 1024 + col;
          float v = acc[mi][ni][r] + bo_ + xres[idx];
          x1f[idx] = v;
          ob0[idx] = f2bf(v);
        }
      }
    }
  } else if (MODE == 2) {
#pragma unroll
    for (int ni = 0; ni < 4; ni++) {
      int col = n0 + wn * 64 + ni * 16 + cl;
      float b1_ = f0[(size_t)e * 4096 + col];
#pragma unroll
      for (int mi = 0; mi < MI; mi++) {
        int pos = pos0 + wm * WR + mi * 16 + rl * 4;
#pragma unroll
        for (int r = 0; r < 4; r++) {
          float v = acc[mi][ni][r] + b1_;
          v = v > 0.0f ? v : 0.0f;
          ob0[(size_t)(seg + pos + r) * 4096 + col] = f2bf(v);
        }
      }
    }
  } else {  // MODE 3: bf16 partials (padded rows included; reduce masks)
#pragma unroll
    for (int ni = 0; ni < 4; ni++) {
      int col = n0 + wn * 64 + ni * 16 + cl;
#pragma unroll
      for (int mi = 0; mi < MI; mi++) {
        int pos = pos0 + wm * WR + mi * 16 + rl * 4;
#pragma unroll
        for (int r = 0; r < 4; r++)
          pout[((size_t)s * HROWS + seg + pos + r) * 1024 + col] = f2bf(acc[mi][ni][r]);
      }
    }
  }
}

// ---------------- FF2 split-K reduce: out = x1f + topp*(p0+p1+b2[e]) ----------------
__global__ __launch_bounds__(256) void reduce3_kernel(
    const u16* __restrict__ P3, const float* __restrict__ x1f,
    const float* __restrict__ topp, const float* __restrict__ b2,
    const int* __restrict__ meta, float* __restrict__ out) {
  int bidx = blockIdx.x;
  int tile = bidx >> 7, rowin = bidx & 127;
  int e = meta[MT_E + tile];
  if (e < 0) return;
  int cnt = meta[MCNT + e], seg = meta[MSEG + e];
  int pos = meta[MT_P0 + tile] + rowin;
  if (pos >= cnt) return;
  int tok = meta[MPERM + seg + pos];
  size_t prow = (size_t)(seg + pos) * 1024;
  float p = topp[tok];
  int c = threadIdx.x * 4;
  ushort4 u0 = *reinterpret_cast<const ushort4*>(&P3[prow + c]);
  ushort4 u1 = *reinterpret_cast<const ushort4*>(&P3[(size_t)HROWS * 1024 + prow + c]);
  float4 xr = *reinterpret_cast<const float4*>(&x1f[(size_t)tok * 1024 + c]);
  float4 bb = *reinterpret_cast<const float4*>(&b2[e * 1024 + c]);
  float4 o;
  o.x = xr.x + p * (bf2f(u0.x) + bf2f(u1.x) + bb.x);
  o.y = xr.y + p * (bf2f(u0.y) + bf2f(u1.y) + bb.y);
  o.z = xr.z + p * (bf2f(u0.z) + bf2f(u1.z) + bb.z);
  o.w = xr.w + p * (bf2f(u0.w) + bf2f(u1.w) + bb.w);
  *reinterpret_cast<float4*>(&out[(size_t)tok * 1024 + c]) = o;
}

// ---------------- flash attention, swapped-operand + staged epilogue ----------------
__global__ __launch_bounds__(256, 4) void attn_kernel(
    const u16* __restrict__ q, const u16* __restrict__ k,
    const u16* __restrict__ vt, u16* __restrict__ attn) {
  __shared__ u16 Ks[2][64 * 64];
  __shared__ u16 Vs[2][64 * 64];
  const int tid = threadIdx.x, lane = tid & 63, w = tid >> 6;
  const int g = lane >> 4, l15 = lane & 15;

  int bb = blockIdx.x;
  int lg = (bb & 7) * 128 + (bb >> 3);
  const int bh = lg >> 4;
  const int qt = lg & 15;
  const size_t qkbase = (size_t)bh * Tn * 64;
  const size_t vtbase = (size_t)bh * 64 * Tn;
  const int qrow0 = qt * 64 + w * 16;

  bf16x8 qf[2];
  {
    const u16* qp = q + qkbase + (size_t)(qrow0 + l15) * 64 + g * 8;
    qf[0] = *reinterpret_cast<const bf16x8*>(qp);
    qf[1] = *reinterpret_cast<const bf16x8*>(qp + 32);
  }

  const u16* gk[2];
  const u16* gv[2];
#pragma unroll
  for (int j = 0; j < 2; j++) {
    int sidx = j * 256 + tid;
    int r = sidx >> 3, p = sidx & 7;
    int c = aswz(r, p);
    gk[j] = k + qkbase + (size_t)r * 64 + c * 8;
    gv[j] = vt + vtbase + (size_t)r * Tn + c * 8;
  }

  auto STAGE = [&](int t) {
    int buf = t & 1;
#pragma unroll
    for (int j = 0; j < 2; j++) {
      int sidx = j * 256 + tid;
      gload16(gk[j] + (size_t)t * 4096, &Ks[buf][sidx * 8]);
      gload16(gv[j] + (size_t)t * 64, &Vs[buf][sidx * 8]);
    }
  };

  f32x4 o[4] = {};
  float mrun = -1e30f, lsum = 0.0f;

  STAGE(0);
  for (int t = 0; t < 16; t++) {
    asm volatile("s_waitcnt vmcnt(0)" ::: "memory");
    __builtin_amdgcn_s_barrier();
    if (t + 1 < 16) STAGE(t + 1);

    const char* Kb = reinterpret_cast<const char*>(&Ks[t & 1][0]);
    const char* Vb = reinterpret_cast<const char*>(&Vs[t & 1][0]);

    f32x4 sk[2][2];
#pragma unroll
    for (int kb = 0; kb < 2; kb++)
#pragma unroll
      for (int m = 0; m < 2; m++) {
        f32x4 sa = {};
#pragma unroll
        for (int ph = 0; ph < 2; ph++) {
          int ksel = kb * 32 + (l15 >> 2) * 8 + m * 4 + (lane & 3);
          int pch = aswz(ksel, g + ph * 4);
          bf16x8 kf = *reinterpret_cast<const bf16x8*>(Kb + ksel * 128 + pch * 16);
          sa = __builtin_amdgcn_mfma_f32_16x16x32_bf16(kf, qf[ph], sa, 0, 0, 0);
        }
        sk[kb][m] = sa;
      }

    float mx = -1e30f;
#pragma unroll
    for (int kb = 0; kb < 2; kb++)
#pragma unroll
      for (int m = 0; m < 2; m++)
#pragma unroll
        for (int r = 0; r < 4; r++) mx = fmaxf(mx, sk[kb][m][r]);
    mx = fmaxf(mx, __shfl_xor(mx, 16));
    mx = fmaxf(mx, __shfl_xor(mx, 32));
    float mn = fmaxf(mrun, mx);
    float rsc = __expf(mrun - mn);
    mrun = mn;

    float pv[2][8];
    float ps = 0.0f;
#pragma unroll
    for (int kb = 0; kb < 2; kb++)
#pragma unroll
      for (int m = 0; m < 2; m++)
#pragma unroll
        for (int r = 0; r < 4; r++) {
          float pe = __expf(sk[kb][m][r] - mn);
          pv[kb][m * 4 + r] = pe;
          ps += pe;
        }
    ps += __shfl_xor(ps, 16);
    ps += __shfl_xor(ps, 32);
    lsum = lsum * rsc + ps;
#pragma unroll
    for (int nf = 0; nf < 4; nf++)
#pragma unroll
      for (int r = 0; r < 4; r++) o[nf][r] *= rsc;

    bf16x8 pf[2];
#pragma unroll
    for (int kb = 0; kb < 2; kb++)
#pragma unroll
      for (int j = 0; j < 8; j++) pf[kb][j] = (__bf16)pv[kb][j];

#pragma unroll
    for (int nf = 0; nf < 4; nf++) {
      int d = nf * 16 + l15;
#pragma unroll
      for (int kb = 0; kb < 2; kb++) {
        int pch = aswz(d, g + kb * 4);
        bf16x8 vf = *reinterpret_cast<const bf16x8*>(Vb + d * 128 + pch * 16);
        o[nf] = __builtin_amdgcn_mfma_f32_16x16x32_bf16(vf, pf[kb], o[nf], 0, 0, 0);
      }
    }
  }

  // staged epilogue: [64 q][64 d] tile in Ks, then ushort8 coalesced stores
  __syncthreads();
  u16* T = &Ks[0][0];
  float inv = 1.0f / lsum;
#pragma unroll
  for (int nf = 0; nf < 4; nf++)
#pragma unroll
    for (int r = 0; r < 4; r++) {
      int row = w * 16 + l15;
      int d = nf * 16 + g * 4 + r;
      int off = (row << 6) + ((((d >> 3) ^ (row & 7)) << 3) | (d & 7));
      T[off] = f2bf(o[nf][r] * inv);
    }
  __syncthreads();
  int b_ = bh >> 4, h_ = bh & 15;
#pragma unroll
  for (int p = 0; p < 2; p++) {
    int idx = p * 256 + tid;
    int row = idx >> 3, ch = idx & 7;
    int pch = ch ^ (row & 7);
    us8 v = *reinterpret_cast<const us8*>(T + (row << 6) + (pch << 3));
    *reinterpret_cast<us8*>(
        &attn[((size_t)(b_ * Tn + qt * 64 + row)) * 1024 + h_ * 64 + ch * 8]) = v;
  }
}

// ---------------- MoE gate: f32 logits, softmax, top-1 ----------------
__global__ __launch_bounds__(256) void gate_kernel(
    const float* __restrict__ x1f, const float* __restrict__ gW,
    const float* __restrict__ gb, float* __restrict__ topp,
    int* __restrict__ tidx, int* __restrict__ meta) {
  int lane = threadIdx.x & 63;
  int n = blockIdx.x * 4 + (threadIdx.x >> 6);
  float acc[8] = {};
  const float* xr = x1f + (size_t)n * 1024;
  for (int kk = 0; kk < 16; kk++) {
    int kcol = kk * 64 + lane;
    float xv = xr[kcol];
    float4 g0 = *reinterpret_cast<const float4*>(&gW[kcol * 8]);
    float4 g1 = *reinterpret_cast<const float4*>(&gW[kcol * 8 + 4]);
    acc[0] = fmaf(xv, g0.x, acc[0]); acc[1] = fmaf(xv, g0.y, acc[1]);
    acc[2] = fmaf(xv, g0.z, acc[2]); acc[3] = fmaf(xv, g0.w, acc[3]);
    acc[4] = fmaf(xv, g1.x, acc[4]); acc[5] = fmaf(xv, g1.y, acc[5]);
    acc[6] = fmaf(xv, g1.z, acc[6]); acc[7] = fmaf(xv, g1.w, acc[7]);
  }
#pragma unroll
  for (int e2 = 0; e2 < 8; e2++)
#pragma unroll
    for (int sh = 1; sh <= 32; sh <<= 1) acc[e2] += __shfl_xor(acc[e2], sh);
  if (lane == 0) {
    float best = -1e30f; int bi = 0;
#pragma unroll
    for (int e2 = 0; e2 < 8; e2++) {
      float lgt = acc[e2] + gb[e2];
      if (lgt > best) { best = lgt; bi = e2; }
    }
    float den = 0.0f;
#pragma unroll
    for (int e2 = 0; e2 < 8; e2++) den += __expf(acc[e2] + gb[e2] - best);
    topp[n] = 1.0f / den;
    tidx[n] = bi;
    atomicAdd(&meta[MCNT + bi], 1);
  }
}

// ---------------- scan: 128-padded segment bases, tile table, aux loss ----------------
__global__ void scan_kernel(int* meta, float* aux_out) {
  if (threadIdx.x == 0) {
    int sb = 0, t = 0;
    float aux = 0.0f;
    for (int e2 = 0; e2 < 8; e2++) {
      meta[MSEG + e2] = sb;
      int c = meta[MCNT + e2];
      int ntile = (c + 127) >> 7;
      for (int i = 0; i < ntile; i++) { meta[MT_E + t] = e2; meta[MT_P0 + t] = i * 128; t++; }
      sb += ntile << 7;
      float fr = (float)c * (1.0f / 4096.0f);
      aux += fr * fr;
    }
    for (; t < MAXT; t++) { meta[MT_E + t] = -1; meta[MT_P0 + t] = 0; }
    aux_out[0] = aux * 8.0f;
  }
}

__global__ __launch_bounds__(256) void scatter_kernel(const int* __restrict__ tidx, int* meta) {
  int n = blockIdx.x * 256 + threadIdx.x;
  int e2 = tidx[n];
  int pos = atomicAdd(&meta[MCUR + e2], 1);
  meta[MPERM + meta[MSEG + e2] + pos] = n;
}

// ---------------- launch ----------------
extern "C" void kernel_launch(void* const* d_in, const int* in_sizes, int n_in,
                              void* d_out, int out_size, void* d_ws, size_t ws_size,
                              hipStream_t stream) {
  const float* x   = (const float*)d_in[0];
  const float* Wq  = (const float*)d_in[2];
  const float* bq  = (const float*)d_in[3];
  const float* Wk  = (const float*)d_in[4];
  const float* bk  = (const float*)d_in[5];
  const float* Wv  = (const float*)d_in[6];
  const float* bv  = (const float*)d_in[7];
  const float* Wo  = (const float*)d_in[8];
  const float* bo  = (const float*)d_in[9];
  const float* ln1a = (const float*)d_in[10];
  const float* ln1b = (const float*)d_in[11];
  const float* gW  = (const float*)d_in[14];
  const float* gb  = (const float*)d_in[15];
  const float* W1  = (const float*)d_in[16];
  const float* b1  = (const float*)d_in[17];
  const float* W2  = (const float*)d_in[18];
  const float* b2  = (const float*)d_in[19];
  float* out = (float*)d_out;
  char* ws = (char*)d_ws;

  u16* wqkvt = (u16*)(ws + WQKVT_O);
  u16* wot   = (u16*)(ws + WOT_O);
  u16* w12t  = (u16*)(ws + W12T_O);
  u16* xn    = (u16*)(ws + XN_O);
  u16* qb    = (u16*)(ws + Q_O);
  u16* kb    = (u16*)(ws + K_O);
  u16* vtb   = (u16*)(ws + VT_O);
  float* x1f = (float*)(ws + X1F_O);
  u16* x1b   = (u16*)(ws + X1B_O);
  u16* p3    = (u16*)(ws + P3_O);
  u16* hb    = (u16*)(ws + H_O);
  float* topp = (float*)(ws + TOPP_O);
  int* tidx  = (int*)(ws + TIDX_O);
  int* meta  = (int*)(ws + META_O);

  hipMemsetAsync(meta + MCNT, 0, 16 * sizeof(int), stream);

  tcast4_kernel<<<dim3(16, 16, 4), 256, 0, stream>>>(Wq, Wk, Wv, Wo, wqkvt, wot);
  tcast_kernel<<<dim3(64, 16, 8), 256, 0, stream>>>(W1, w12t, 1024, 4096,
                                                    (long)1024 * 4096, (long)4096 * 1024);

  ln_kernel<<<4096, 256, 0, stream>>>(x, ln1a, ln1b, xn);
  gemm3_k<0, 128, 4, 1><<<768, 256, 0, stream>>>(xn, wqkvt, bq, bk, bv, nullptr, nullptr,
                                                 qb, kb, vtb, nullptr, meta);
  attn_kernel<<<1024, 256, 0, stream>>>(qb, kb, vtb, xn);  // xn reused as attn-out
  gemm3_k<1, 64, 4, 1><<<512, 256, 0, stream>>>(xn, wot, bo, nullptr, nullptr, x, x1f,
                                                x1b, nullptr, nullptr, nullptr, meta);
  gate_kernel<<<1024, 256, 0, stream>>>(x1f, gW, gb, topp, tidx, meta);
  scan_kernel<<<1, 64, 0, stream>>>(meta, out + (size_t)Nn * Dn);
  scatter_kernel<<<16, 256, 0, stream>>>(tidx, meta);
  gemm3_k<2, 128, 4, 1><<<1280, 256, 0, stream>>>(x1b, w12t, b1, nullptr, nullptr, nullptr,
                                                  nullptr, hb, nullptr, nullptr, nullptr, meta);
  tcast_kernel<<<dim3(16, 64, 8), 256, 0, stream>>>(W2, w12t, 4096, 1024,
                                                    (long)4096 * 1024, (long)1024 * 4096);
  gemm3_k<3, 128, 2, 2><<<640, 256, 0, stream>>>(hb, w12t, nullptr, nullptr, nullptr, nullptr,
                                                 nullptr, nullptr, nullptr, nullptr, p3, meta);
  reduce3_kernel<<<MAXT * 128, 256, 0, stream>>>(p3, x1f, topp, b2, meta, out);
}